// Round 1
// baseline (546.364 us; speedup 1.0000x reference)
//
#include <hip/hip_runtime.h>

#define NN 10000
#define NE 640000

static __device__ __forceinline__ float silu_f(float x) {
    return x / (1.f + __expf(-x));
}

// ---------------- Kernel 1: per-node precompute -----------------------------
// A[n] = node_feat[n] @ W_e1[0:64]     (h_src part of edge MLP layer 1)
// B[n] = node_feat[n] @ W_e1[64:128]   (h_dst part)
// K[n] = node_feat[n] @ W_k[0:64]      (h_src part of key)
// Q[n] = node_feat[n] @ W_q            (query)
__global__ __launch_bounds__(256) void node_pre_kernel(
    const float* __restrict__ node_feat,
    const float* __restrict__ W_e1,   // [145][64]
    const float* __restrict__ W_k,    // [81][64]
    const float* __restrict__ W_q,    // [64][64]
    float* __restrict__ A, float* __restrict__ B,
    float* __restrict__ Kt, float* __restrict__ Qt)
{
    __shared__ float sW1a[64*64];
    __shared__ float sW1b[64*64];
    __shared__ float sWk[64*64];
    __shared__ float sWq[64*64];
    __shared__ __align__(16) float sx[4][64];

    for (int i = threadIdx.x; i < 64*64; i += 256) {
        sW1a[i] = W_e1[i];
        sW1b[i] = W_e1[64*64 + i];
        sWk[i]  = W_k[i];
        sWq[i]  = W_q[i];
    }
    __syncthreads();

    const int wid = threadIdx.x >> 6;
    const int lane = threadIdx.x & 63;
    for (int n = blockIdx.x * 4 + wid; n < NN; n += gridDim.x * 4) {
        sx[wid][lane] = node_feat[n * 64 + lane];
        float a = 0.f, b = 0.f, k = 0.f, q = 0.f;
        #pragma unroll
        for (int i = 0; i < 64; i += 4) {
            float4 x4 = *(const float4*)&sx[wid][i];
            a += x4.x * sW1a[(i+0)*64+lane] + x4.y * sW1a[(i+1)*64+lane]
               + x4.z * sW1a[(i+2)*64+lane] + x4.w * sW1a[(i+3)*64+lane];
            b += x4.x * sW1b[(i+0)*64+lane] + x4.y * sW1b[(i+1)*64+lane]
               + x4.z * sW1b[(i+2)*64+lane] + x4.w * sW1b[(i+3)*64+lane];
            k += x4.x * sWk[(i+0)*64+lane] + x4.y * sWk[(i+1)*64+lane]
               + x4.z * sWk[(i+2)*64+lane] + x4.w * sWk[(i+3)*64+lane];
            q += x4.x * sWq[(i+0)*64+lane] + x4.y * sWq[(i+1)*64+lane]
               + x4.z * sWq[(i+2)*64+lane] + x4.w * sWq[(i+3)*64+lane];
        }
        A[n*64+lane] = a; B[n*64+lane] = b; Kt[n*64+lane] = k; Qt[n*64+lane] = q;
    }
}

// ---------------- Kernel 2: edge pass (the heavy one) -----------------------
// wave-per-edge, lane = feature. Softmax via exp(e) without max subtraction:
//   hacc[d] += exp(e) * msg ;  denom[d] += exp(e)
__global__ __launch_bounds__(256) void edge_kernel(
    const float* __restrict__ coord,
    const float* __restrict__ edge_feat,
    const float* __restrict__ W_e1, const float* __restrict__ b_e1,
    const float* __restrict__ W_e2, const float* __restrict__ b_e2,
    const float* __restrict__ W_k,
    const int* __restrict__ src, const int* __restrict__ dst,
    const float* __restrict__ A, const float* __restrict__ B,
    const float* __restrict__ Kt, const float* __restrict__ Qt,
    float* __restrict__ hacc, float* __restrict__ denom)
{
    __shared__ __align__(16) float sh1[4][64];
    __shared__ __align__(16) float sef[4][16];

    const int wid = threadIdx.x >> 6;
    const int lane = threadIdx.x & 63;

    // Per-lane register-cached weight columns (lane j only ever needs col j).
    float w2col[64];
    #pragma unroll
    for (int i = 0; i < 64; i++) w2col[i] = W_e2[i*64 + lane];
    float w1e[16], wke[16];
    #pragma unroll
    for (int k = 0; k < 16; k++) {
        w1e[k] = W_e1[(129 + k)*64 + lane];  // edge_feat rows of W_e1
        wke[k] = W_k[(65 + k)*64 + lane];    // edge_feat rows of W_k
    }
    const float w1d = W_e1[128*64 + lane];   // dist row of W_e1
    const float wkd = W_k[64*64 + lane];     // dist row of W_k
    const float b1 = b_e1[lane];
    const float b2 = b_e2[lane];

    for (int e = blockIdx.x * 4 + wid; e < NE; e += gridDim.x * 4) {
        const int s = src[e];
        const int d = dst[e];
        const float dx = coord[s*3+0] - coord[d*3+0];
        const float dy = coord[s*3+1] - coord[d*3+1];
        const float dz = coord[s*3+2] - coord[d*3+2];
        const float dist = sqrtf(dx*dx + dy*dy + dz*dz);

        if (lane < 16) sef[wid][lane] = edge_feat[(long)e*16 + lane];

        float acc1 = b1 + A[s*64 + lane] + B[d*64 + lane] + dist * w1d;
        float kacc = Kt[s*64 + lane] + dist * wkd;
        #pragma unroll
        for (int k = 0; k < 16; k += 4) {
            float4 e4 = *(const float4*)&sef[wid][k];
            acc1 += e4.x*w1e[k+0] + e4.y*w1e[k+1] + e4.z*w1e[k+2] + e4.w*w1e[k+3];
            kacc += e4.x*wke[k+0] + e4.y*wke[k+1] + e4.z*wke[k+2] + e4.w*wke[k+3];
        }
        const float h1 = silu_f(acc1);
        sh1[wid][lane] = h1;

        // attention score: dot(msg_k, Q[dst]) / 8
        float p = kacc * Qt[d*64 + lane];
        #pragma unroll
        for (int off = 32; off; off >>= 1) p += __shfl_xor(p, off);
        const float w = __expf(p * 0.125f);

        float acc2 = b2;
        #pragma unroll
        for (int i = 0; i < 64; i += 4) {
            float4 h4 = *(const float4*)&sh1[wid][i];
            acc2 += h4.x*w2col[i+0] + h4.y*w2col[i+1]
                  + h4.z*w2col[i+2] + h4.w*w2col[i+3];
        }
        const float msg = silu_f(acc2);

        atomicAdd(&hacc[(long)d*64 + lane], w * msg);
        if (lane == 0) atomicAdd(&denom[d], w);
    }
}

// ---------------- Kernel 3: node MLP ----------------------------------------
__global__ __launch_bounds__(256) void node_out_kernel(
    const float* __restrict__ node_feat,
    const float* __restrict__ W_n1, const float* __restrict__ b_n1,
    const float* __restrict__ W_n2, const float* __restrict__ b_n2,
    const float* __restrict__ hacc, const float* __restrict__ denom,
    float* __restrict__ out)
{
    __shared__ float sWn1[128*64];  // 32 KB
    __shared__ float sWn2[64*64];   // 16 KB
    __shared__ __align__(16) float sx[4][64], sg[4][64], st[4][64];

    for (int i = threadIdx.x; i < 128*64; i += 256) sWn1[i] = W_n1[i];
    for (int i = threadIdx.x; i < 64*64; i += 256)  sWn2[i] = W_n2[i];
    __syncthreads();

    const int wid = threadIdx.x >> 6;
    const int lane = threadIdx.x & 63;
    for (int n = blockIdx.x * 4 + wid; n < NN; n += gridDim.x * 4) {
        sx[wid][lane] = node_feat[n*64 + lane];
        const float dn = denom[n];
        const float g = (dn > 0.f) ? hacc[n*64 + lane] / dn : 0.f;
        sg[wid][lane] = g;

        float acc = b_n1[lane];
        #pragma unroll
        for (int i = 0; i < 64; i += 4) {
            float4 x4 = *(const float4*)&sx[wid][i];
            float4 g4 = *(const float4*)&sg[wid][i];
            acc += x4.x*sWn1[(i+0)*64+lane] + x4.y*sWn1[(i+1)*64+lane]
                 + x4.z*sWn1[(i+2)*64+lane] + x4.w*sWn1[(i+3)*64+lane];
            acc += g4.x*sWn1[(64+i+0)*64+lane] + g4.y*sWn1[(64+i+1)*64+lane]
                 + g4.z*sWn1[(64+i+2)*64+lane] + g4.w*sWn1[(64+i+3)*64+lane];
        }
        const float t = silu_f(acc);
        st[wid][lane] = t;

        float acc2 = b_n2[lane];
        #pragma unroll
        for (int i = 0; i < 64; i += 4) {
            float4 t4 = *(const float4*)&st[wid][i];
            acc2 += t4.x*sWn2[(i+0)*64+lane] + t4.y*sWn2[(i+1)*64+lane]
                  + t4.z*sWn2[(i+2)*64+lane] + t4.w*sWn2[(i+3)*64+lane];
        }
        out[n*64 + lane] = acc2;
    }
}

// ---------------- launch ----------------------------------------------------
extern "C" void kernel_launch(void* const* d_in, const int* in_sizes, int n_in,
                              void* d_out, int out_size, void* d_ws, size_t ws_size,
                              hipStream_t stream) {
    const float* node_feat = (const float*)d_in[0];
    const float* coord     = (const float*)d_in[1];
    const float* edge_feat = (const float*)d_in[2];
    const float* W_e1 = (const float*)d_in[3];
    const float* b_e1 = (const float*)d_in[4];
    const float* W_e2 = (const float*)d_in[5];
    const float* b_e2 = (const float*)d_in[6];
    const float* W_n1 = (const float*)d_in[7];
    const float* b_n1 = (const float*)d_in[8];
    const float* W_n2 = (const float*)d_in[9];
    const float* b_n2 = (const float*)d_in[10];
    const float* W_q  = (const float*)d_in[11];
    const float* W_k  = (const float*)d_in[12];
    const int* src = (const int*)d_in[13];
    const int* dst = (const int*)d_in[14];
    float* out = (float*)d_out;

    float* ws = (float*)d_ws;
    float* A     = ws;                 // [NN,64]
    float* B     = ws + 1*NN*64;       // [NN,64]
    float* Kt    = ws + 2*NN*64;       // [NN,64]
    float* Qt    = ws + 3*NN*64;       // [NN,64]
    float* hacc  = ws + 4*NN*64;       // [NN,64]
    float* denom = ws + 5*NN*64;       // [NN]

    // zero the accumulators (hacc and denom are contiguous)
    hipMemsetAsync(hacc, 0, (size_t)(NN*64 + NN) * sizeof(float), stream);

    node_pre_kernel<<<2500, 256, 0, stream>>>(node_feat, W_e1, W_k, W_q, A, B, Kt, Qt);
    edge_kernel<<<4096, 256, 0, stream>>>(coord, edge_feat, W_e1, b_e1, W_e2, b_e2,
                                          W_k, src, dst, A, B, Kt, Qt, hacc, denom);
    node_out_kernel<<<2500, 256, 0, stream>>>(node_feat, W_n1, b_n1, W_n2, b_n2,
                                              hacc, denom, out);
}

// Round 2
// 393.428 us; speedup vs baseline: 1.3887x; 1.3887x over previous
//
#include <hip/hip_runtime.h>

#define NN 10000
#define NE 640000

typedef __attribute__((ext_vector_type(8))) short bf16x8;   // 8 bf16 in 4 VGPRs
typedef __attribute__((ext_vector_type(4))) float f32x4;

static __device__ __forceinline__ float silu_f(float x) {
    return x / (1.f + __expf(-x));
}
static __device__ __forceinline__ short f2bf(float x) {   // RNE f32->bf16
    union { float f; unsigned u; } v; v.f = x;
    unsigned r = (v.u + 0x7FFF + ((v.u >> 16) & 1)) >> 16;
    return (short)r;
}
static __device__ __forceinline__ float bf2f(short h) {
    union { float f; unsigned u; } v; v.u = ((unsigned)(unsigned short)h) << 16;
    return v.f;
}

// ---------------- Kernel 1: per-node precompute -----------------------------
// A[n] = nf@W_e1[0:64], B[n] = nf@W_e1[64:128], Kt[n] = nf@W_k[0:64],
// Qt[n] = nf@W_q, WQn[n] = wkd.Qt[n], EQn[n][k] = Wke[k,:].Qt[n]
__global__ __launch_bounds__(256) void node_pre_kernel(
    const float* __restrict__ node_feat,
    const float* __restrict__ W_e1,   // [145][64]
    const float* __restrict__ W_k,    // [81][64]
    const float* __restrict__ W_q,    // [64][64]
    float* __restrict__ A, float* __restrict__ B,
    float* __restrict__ Kt, float* __restrict__ Qt,
    float* __restrict__ EQn, float* __restrict__ WQn)
{
    __shared__ float sW1a[64*64];
    __shared__ float sW1b[64*64];
    __shared__ float sWk[64*64];
    __shared__ float sWq[64*64];
    __shared__ __align__(16) float sx[4][64];

    for (int i = threadIdx.x; i < 64*64; i += 256) {
        sW1a[i] = W_e1[i];
        sW1b[i] = W_e1[64*64 + i];
        sWk[i]  = W_k[i];
        sWq[i]  = W_q[i];
    }
    __syncthreads();

    const int wid = threadIdx.x >> 6;
    const int lane = threadIdx.x & 63;
    for (int n = blockIdx.x * 4 + wid; n < NN; n += gridDim.x * 4) {
        sx[wid][lane] = node_feat[n * 64 + lane];
        float a = 0.f, b = 0.f, k = 0.f, q = 0.f;
        #pragma unroll
        for (int i = 0; i < 64; i += 4) {
            float4 x4 = *(const float4*)&sx[wid][i];
            a += x4.x * sW1a[(i+0)*64+lane] + x4.y * sW1a[(i+1)*64+lane]
               + x4.z * sW1a[(i+2)*64+lane] + x4.w * sW1a[(i+3)*64+lane];
            b += x4.x * sW1b[(i+0)*64+lane] + x4.y * sW1b[(i+1)*64+lane]
               + x4.z * sW1b[(i+2)*64+lane] + x4.w * sW1b[(i+3)*64+lane];
            k += x4.x * sWk[(i+0)*64+lane] + x4.y * sWk[(i+1)*64+lane]
               + x4.z * sWk[(i+2)*64+lane] + x4.w * sWk[(i+3)*64+lane];
            q += x4.x * sWq[(i+0)*64+lane] + x4.y * sWq[(i+1)*64+lane]
               + x4.z * sWq[(i+2)*64+lane] + x4.w * sWq[(i+3)*64+lane];
        }
        A[n*64+lane] = a; B[n*64+lane] = b; Kt[n*64+lane] = k; Qt[n*64+lane] = q;

        // WQn = sum_c W_k[64][c] * q_c   (q lives lane=c)
        {
            float p = W_k[64*64 + lane] * q;
            #pragma unroll
            for (int off = 32; off; off >>= 1) p += __shfl_xor(p, off);
            if (lane == 0) WQn[n] = p;
        }
        // EQn[k] = sum_c W_k[65+k][c] * q_c
        #pragma unroll
        for (int kk = 0; kk < 16; kk++) {
            float p = W_k[(65+kk)*64 + lane] * q;
            #pragma unroll
            for (int off = 32; off; off >>= 1) p += __shfl_xor(p, off);
            if (lane == 0) EQn[n*16 + kk] = p;
        }
    }
}

// ---------------- Kernel 2: MFMA edge pass ----------------------------------
// 64-edge tiles; block=256 (4 waves, wave w owns M-tile w = 16 edges).
__global__ __launch_bounds__(256) void edge_kernel(
    const float* __restrict__ coord,
    const float* __restrict__ ef_g,
    const float* __restrict__ W_e1, const float* __restrict__ b_e1,
    const float* __restrict__ W_e2, const float* __restrict__ b_e2,
    const int* __restrict__ src, const int* __restrict__ dst,
    const float* __restrict__ A, const float* __restrict__ B,
    const float* __restrict__ Kt, const float* __restrict__ Qt,
    const float* __restrict__ EQn, const float* __restrict__ WQn,
    float* __restrict__ hacc, float* __restrict__ denom)
{
    __shared__ short sW1xT[64*40];   // [c][k0..31] bf16, k:16 ef rows,16=dist,17=bias,rest 0
    __shared__ short sW2T [64*72];   // [c][k0..63] bf16 (W_e2 transposed)
    __shared__ short sX   [64*40];   // [e][k] bf16: ef(16), dist, 1, 0-pad
    __shared__ short sH1  [64*72];   // [e][c] bf16 after silu
    __shared__ float sscore[4][64];
    __shared__ float sw_[64];
    __shared__ float sdist[64];
    __shared__ float swq[64];
    __shared__ float seqn[64*20];    // [e][16] padded to 20
    __shared__ int   ssrc[64], sdstl[64];

    const int tid = threadIdx.x;
    const int w = tid >> 6, l = tid & 63;
    const int cl = l & 15, rg = l >> 4;

    // ---- one-time staging: zero pads, then fill weights ----
    for (int i = tid; i < 64*40; i += 256) { sW1xT[i] = 0; sX[i] = 0; }
    __syncthreads();
    for (int i = tid; i < 64*18; i += 256) {     // i = k*64 + c
        int k = i >> 6, c = i & 63;
        float v;
        if (k < 16)       v = W_e1[(129 + k)*64 + c];
        else if (k == 16) v = W_e1[128*64 + c];
        else              v = b_e1[c];
        sW1xT[c*40 + k] = f2bf(v);
    }
    for (int i = tid; i < 64*64; i += 256) {     // i = k*64 + c
        int k = i >> 6, c = i & 63;
        sW2T[c*72 + k] = f2bf(W_e2[k*64 + c]);
    }
    __syncthreads();

    for (int t = blockIdx.x * 4; t < blockIdx.x * 4 + 4; ++t) {
        const int ebase = t * 64;
        const int s_l = src[ebase + l];
        const int d_l = dst[ebase + l];

        // ---------- G1: partial score dots + per-wave duties ----------
        {
            const float4* kp = (const float4*)(Kt + (size_t)s_l*64 + w*16);
            const float4* qp = (const float4*)(Qt + (size_t)d_l*64 + w*16);
            float p = 0.f;
            #pragma unroll
            for (int j = 0; j < 4; j++) {
                float4 a4 = kp[j], b4 = qp[j];
                p += a4.x*b4.x + a4.y*b4.y + a4.z*b4.z + a4.w*b4.w;
            }
            sscore[w][l] = p;
        }
        if (w == 1) {
            const float4* efp = (const float4*)(ef_g + (size_t)ebase*16);
            #pragma unroll
            for (int i = 0; i < 4; i++) {
                int idx = i*64 + l, e = idx >> 2, part = idx & 3;
                float4 v = efp[idx];
                short* dp = &sX[e*40 + part*4];
                dp[0] = f2bf(v.x); dp[1] = f2bf(v.y);
                dp[2] = f2bf(v.z); dp[3] = f2bf(v.w);
            }
            sX[l*40 + 17] = (short)0x3F80;  // 1.0 bf16 (bias column)
        } else if (w == 2) {
            float dx = coord[s_l*3+0] - coord[d_l*3+0];
            float dy = coord[s_l*3+1] - coord[d_l*3+1];
            float dz = coord[s_l*3+2] - coord[d_l*3+2];
            float dist = sqrtf(dx*dx + dy*dy + dz*dz);
            sdist[l] = dist;
            sX[l*40 + 16] = f2bf(dist);
        } else if (w == 3) {
            ssrc[l] = s_l; sdstl[l] = d_l;
            swq[l] = WQn[d_l];
            const float4* ep = (const float4*)(EQn + (size_t)d_l*16);
            #pragma unroll
            for (int i = 0; i < 4; i++) *(float4*)&seqn[l*20 + i*4] = ep[i];
        }
        __syncthreads();

        // ---------- finalize score (wave 0) while all waves start M1 ----------
        if (w == 0) {
            float es = sscore[0][l] + sscore[1][l] + sscore[2][l] + sscore[3][l]
                     + sdist[l] * swq[l];
            #pragma unroll
            for (int c = 0; c < 16; c++)
                es += bf2f(sX[l*40 + c]) * seqn[l*20 + c];
            float wexp = __expf(es * 0.125f);
            sw_[l] = wexp;
            atomicAdd(&denom[sdstl[l]], wexp);
        }

        // ---------- M1: h1 = silu( A[s]+B[d] + X @ W1x ) ----------
        int sR[4], dR[4];
        #pragma unroll
        for (int r = 0; r < 4; r++) {
            int row = w*16 + rg*4 + r;
            sR[r] = ssrc[row]; dR[r] = sdstl[row];
        }
        f32x4 acc1[4];
        #pragma unroll
        for (int nt = 0; nt < 4; nt++) {
            #pragma unroll
            for (int r = 0; r < 4; r++) {
                int col = nt*16 + cl;
                acc1[nt][r] = A[(size_t)sR[r]*64 + col] + B[(size_t)dR[r]*64 + col];
            }
        }
        bf16x8 ax = *(const bf16x8*)&sX[(w*16 + cl)*40 + rg*8];
        #pragma unroll
        for (int nt = 0; nt < 4; nt++) {
            bf16x8 bw = *(const bf16x8*)&sW1xT[(nt*16 + cl)*40 + rg*8];
            acc1[nt] = __builtin_amdgcn_mfma_f32_16x16x32_bf16(ax, bw, acc1[nt], 0, 0, 0);
        }
        #pragma unroll
        for (int nt = 0; nt < 4; nt++) {
            #pragma unroll
            for (int r = 0; r < 4; r++) {
                int row = w*16 + rg*4 + r, col = nt*16 + cl;
                sH1[row*72 + col] = f2bf(silu_f(acc1[nt][r]));
            }
        }
        __syncthreads();

        // ---------- M2: msg = silu( b2 + H1 @ W2 ); atomic scatter ----------
        f32x4 acc2[4];
        #pragma unroll
        for (int nt = 0; nt < 4; nt++) {
            float b2v = b_e2[nt*16 + cl];
            acc2[nt][0] = b2v; acc2[nt][1] = b2v; acc2[nt][2] = b2v; acc2[nt][3] = b2v;
        }
        bf16x8 ah0 = *(const bf16x8*)&sH1[(w*16 + cl)*72 + rg*8];
        bf16x8 ah1 = *(const bf16x8*)&sH1[(w*16 + cl)*72 + 32 + rg*8];
        #pragma unroll
        for (int nt = 0; nt < 4; nt++) {
            bf16x8 b0 = *(const bf16x8*)&sW2T[(nt*16 + cl)*72 + rg*8];
            bf16x8 b1 = *(const bf16x8*)&sW2T[(nt*16 + cl)*72 + 32 + rg*8];
            acc2[nt] = __builtin_amdgcn_mfma_f32_16x16x32_bf16(ah0, b0, acc2[nt], 0, 0, 0);
            acc2[nt] = __builtin_amdgcn_mfma_f32_16x16x32_bf16(ah1, b1, acc2[nt], 0, 0, 0);
        }
        float wr[4]; int dD[4];
        #pragma unroll
        for (int r = 0; r < 4; r++) {
            int row = w*16 + rg*4 + r;
            wr[r] = sw_[row]; dD[r] = sdstl[row];
        }
        #pragma unroll
        for (int nt = 0; nt < 4; nt++) {
            #pragma unroll
            for (int r = 0; r < 4; r++) {
                float msg = silu_f(acc2[nt][r]);
                atomicAdd(&hacc[(size_t)dD[r]*64 + nt*16 + cl], wr[r] * msg);
            }
        }
        __syncthreads();   // protect ssrc/sdstl/sw_/sH1 before next tile's G1
    }
}

// ---------------- Kernel 3: node MLP ----------------------------------------
__global__ __launch_bounds__(256) void node_out_kernel(
    const float* __restrict__ node_feat,
    const float* __restrict__ W_n1, const float* __restrict__ b_n1,
    const float* __restrict__ W_n2, const float* __restrict__ b_n2,
    const float* __restrict__ hacc, const float* __restrict__ denom,
    float* __restrict__ out)
{
    __shared__ float sWn1[128*64];
    __shared__ float sWn2[64*64];
    __shared__ __align__(16) float sx[4][64], sg[4][64], st[4][64];

    for (int i = threadIdx.x; i < 128*64; i += 256) sWn1[i] = W_n1[i];
    for (int i = threadIdx.x; i < 64*64; i += 256)  sWn2[i] = W_n2[i];
    __syncthreads();

    const int wid = threadIdx.x >> 6;
    const int lane = threadIdx.x & 63;
    for (int n = blockIdx.x * 4 + wid; n < NN; n += gridDim.x * 4) {
        sx[wid][lane] = node_feat[n*64 + lane];
        const float dn = denom[n];
        const float g = (dn > 0.f) ? hacc[n*64 + lane] / dn : 0.f;
        sg[wid][lane] = g;

        float acc = b_n1[lane];
        #pragma unroll
        for (int i = 0; i < 64; i += 4) {
            float4 x4 = *(const float4*)&sx[wid][i];
            float4 g4 = *(const float4*)&sg[wid][i];
            acc += x4.x*sWn1[(i+0)*64+lane] + x4.y*sWn1[(i+1)*64+lane]
                 + x4.z*sWn1[(i+2)*64+lane] + x4.w*sWn1[(i+3)*64+lane];
            acc += g4.x*sWn1[(64+i+0)*64+lane] + g4.y*sWn1[(64+i+1)*64+lane]
                 + g4.z*sWn1[(64+i+2)*64+lane] + g4.w*sWn1[(64+i+3)*64+lane];
        }
        const float tt = silu_f(acc);
        st[wid][lane] = tt;

        float acc2 = b_n2[lane];
        #pragma unroll
        for (int i = 0; i < 64; i += 4) {
            float4 t4 = *(const float4*)&st[wid][i];
            acc2 += t4.x*sWn2[(i+0)*64+lane] + t4.y*sWn2[(i+1)*64+lane]
                  + t4.z*sWn2[(i+2)*64+lane] + t4.w*sWn2[(i+3)*64+lane];
        }
        out[n*64 + lane] = acc2;
    }
}

// ---------------- launch ----------------------------------------------------
extern "C" void kernel_launch(void* const* d_in, const int* in_sizes, int n_in,
                              void* d_out, int out_size, void* d_ws, size_t ws_size,
                              hipStream_t stream) {
    const float* node_feat = (const float*)d_in[0];
    const float* coord     = (const float*)d_in[1];
    const float* edge_feat = (const float*)d_in[2];
    const float* W_e1 = (const float*)d_in[3];
    const float* b_e1 = (const float*)d_in[4];
    const float* W_e2 = (const float*)d_in[5];
    const float* b_e2 = (const float*)d_in[6];
    const float* W_n1 = (const float*)d_in[7];
    const float* b_n1 = (const float*)d_in[8];
    const float* W_n2 = (const float*)d_in[9];
    const float* b_n2 = (const float*)d_in[10];
    const float* W_q  = (const float*)d_in[11];
    const float* W_k  = (const float*)d_in[12];
    const int* src = (const int*)d_in[13];
    const int* dst = (const int*)d_in[14];
    float* out = (float*)d_out;

    float* ws = (float*)d_ws;
    float* A     = ws;                  // [NN*64]
    float* B     = ws + 640000;         // [NN*64]
    float* Kt    = ws + 1280000;        // [NN*64]
    float* Qt    = ws + 1920000;        // [NN*64]
    float* hacc  = ws + 2560000;        // [NN*64]
    float* denom = ws + 3200000;        // [NN]
    float* EQn   = ws + 3210000;        // [NN*16]
    float* WQn   = ws + 3370000;        // [NN]

    // zero hacc + denom (contiguous)
    hipMemsetAsync(hacc, 0, (size_t)(640000 + 10000) * sizeof(float), stream);

    node_pre_kernel<<<2500, 256, 0, stream>>>(node_feat, W_e1, W_k, W_q,
                                              A, B, Kt, Qt, EQn, WQn);
    edge_kernel<<<2500, 256, 0, stream>>>(coord, edge_feat, W_e1, b_e1, W_e2, b_e2,
                                          src, dst, A, B, Kt, Qt, EQn, WQn,
                                          hacc, denom);
    node_out_kernel<<<2500, 256, 0, stream>>>(node_feat, W_n1, b_n1, W_n2, b_n2,
                                              hacc, denom, out);
}